// Round 12
// baseline (169.750 us; speedup 1.0000x reference)
//
#include <hip/hip_runtime.h>
#include <math.h>

#define T_TOKENS 8192
#define NEXP 256
#define DIM 7168
#define NSPLIT 4
#define KSPL (DIM / NSPLIT)      // 1792
#define NITER (KSPL / 32)        // 56 K-steps per bz
#define NEG_INF (-3.0e38f)

typedef _Float16 f16;
typedef _Float16 f16x8 __attribute__((ext_vector_type(8)));
typedef __fp16 h16x2 __attribute__((ext_vector_type(2)));
typedef float f32x4 __attribute__((ext_vector_type(4)));
typedef float f32x16 __attribute__((ext_vector_type(16)));

#define AS1 __attribute__((address_space(1)))
#define AS3 __attribute__((address_space(3)))
typedef const AS1 f16x8* gf16x8p;

// ws: [W' frag-tiled f16 7.34MB][part f32 (NSPLIT x T x E) 33.5MB]
// W' 32KB chunk per K-step T; unit = (kk*2+p)*8 + ntg (1KB, lane-contiguous)
#define WTILED_BYTES (2 * NEXP * DIM * 2)   // 7,340,032
#define PART_OFF WTILED_BYTES
#define UNSCALE 5.9604644775390625e-8f      // 2^-24 exact
#define STG 8192                             // A stage: 64 rows x 32 k f32, fragment order

// ---------------- prologue: w (f32) -> 32x32-frag-tiled 2-plane f16 image ----------------
__global__ __launch_bounds__(256) void wconvert(const float* __restrict__ w,
                                                char* __restrict__ wt) {
    const int n = blockIdx.x * 256 + threadIdx.x;   // 0 .. 229375
    const int K8 = n % 896;                         // k-octet
    const int e = n / 896;                          // expert 0..255
    const f32x4 u0 = *(const f32x4*)(w + (size_t)e * DIM + K8 * 8);
    const f32x4 u1 = *(const f32x4*)(w + (size_t)e * DIM + K8 * 8 + 4);
    float c[8] = {u0[0]*4096.f, u0[1]*4096.f, u0[2]*4096.f, u0[3]*4096.f,
                  u1[0]*4096.f, u1[1]*4096.f, u1[2]*4096.f, u1[3]*4096.f};
    f16x8 h, g;
#pragma unroll
    for (int j = 0; j < 4; ++j) {
        h16x2 hp = __builtin_amdgcn_cvt_pkrtz(c[2*j], c[2*j+1]);
        float r0 = c[2*j]   - (float)hp[0];
        float r1 = c[2*j+1] - (float)hp[1];
        h16x2 gp = __builtin_amdgcn_cvt_pkrtz(r0, r1);
        h[2*j] = (f16)hp[0]; h[2*j+1] = (f16)hp[1];
        g[2*j] = (f16)gp[0]; g[2*j+1] = (f16)gp[1];
    }
    const int T = K8 >> 2;                  // K-step
    const int kk = (K8 >> 1) & 1;
    const int lhi = K8 & 1;
    const int ntg = e >> 5, l31 = e & 31;
    char* base = wt + (size_t)T * 32768 + ntg * 1024 + lhi * 512 + l31 * 16;
    *(f16x8*)(base + (kk * 2 + 0) * 8192) = h;
    *(f16x8*)(base + (kk * 2 + 1) * 8192) = g;
}

// ---------------- GEMM: fragment-order A (ring-3), W->reg, 1 barrier/K-step ----------------
// grid 512 (2/CU); 512 threads = 8 waves; BM=64, wave tile 64x32 (mt=2, wcn=wave).
// A LDS image (8KB/stage): unit(mt,kk,j)=mt*4+kk*2+j, 1KB lane-contiguous:
//   lane l holds x[bm*64+mt*32+(l&31)][32T + kk*16 + (l>>5)*8 + j*4 ..+3]
// Sync proof: per-wave queue at BODY(T) vmcnt(1) = [A(T), W(T)x4, A(T+1)] ->
//   drains own A(T)+W(T); s_barrier => ALL waves' A(T) landed. Stage A(T+2)
//   (issued after barrier) targets buf[(T+2)%3] = buf computed at T-1; every
//   wave finished COMPUTE(T-1) before BARRIER(T) in program order => no race.
__global__ __launch_bounds__(512, 4) void gemm_fo(
    const float* __restrict__ x, const char* __restrict__ wt,
    float* __restrict__ part) {
    __shared__ char smem[3 * STG];
    const int tid = threadIdx.x;
    const int lane = tid & 63;
    const int wcn = tid >> 6;                // wave = output column tile 0..7
    // XCD-pin: xcd -> (bz, bm-half); W' slice (1.83MB) stays in that XCD's L2
    const int b = blockIdx.x;
    const int xcd = b & 7;
    const int bz = xcd >> 1;
    const int bm = (xcd & 1) * 64 + (b >> 3);   // 0..127 (BM=64 rows)
    const int l31 = lane & 31, lhi = lane >> 5;

    const char* xc = (const char*)x;

    // A staging: wave wcn stages unit u=wcn, per-lane scattered source (fragment order)
    const int mt_s = wcn >> 2, kk_s = (wcn >> 1) & 1, j_s = wcn & 1;
    const int aoff = ((bm * 64 + mt_s * 32 + l31) * DIM + bz * KSPL
                      + kk_s * 16 + lhi * 8 + j_s * 4) * 4;
    const int ldsA = wcn * 1024;

    // W fragments: this wave's column tile = unit (kk*2+p)*8 + wcn
    const AS1 char* wq = (const AS1 char*)(wt + (size_t)bz * NITER * 32768
                                           + wcn * 1024 + lane * 16);

    f32x16 acc[2];
#pragma unroll
    for (int mt = 0; mt < 2; ++mt)
#pragma unroll
        for (int r = 0; r < 16; ++r) acc[mt][r] = 0.0f;

    f16x8 wA[2][2], wB[2][2];

#define LOAD_W(T, WDST)                                                         \
    {                                                                           \
        _Pragma("unroll")                                                       \
        for (int kk = 0; kk < 2; ++kk)                                          \
            _Pragma("unroll")                                                   \
            for (int p = 0; p < 2; ++p)                                         \
                WDST[kk][p] = *(gf16x8p)(wq + (size_t)(T) * 32768 + (kk * 2 + p) * 8192); \
    }

#define COMPUTE(CB, W)                                                          \
    {                                                                           \
        _Pragma("unroll")                                                       \
        for (int kk = 0; kk < 2; ++kk) {                                        \
            _Pragma("unroll")                                                   \
            for (int mt = 0; mt < 2; ++mt) {                                    \
                const f32x4 v0 = *(const f32x4*)(smem + (CB) + (mt * 4 + kk * 2 + 0) * 1024 + lane * 16); \
                const f32x4 v1 = *(const f32x4*)(smem + (CB) + (mt * 4 + kk * 2 + 1) * 1024 + lane * 16); \
                float c[8] = {v0[0]*4096.f, v0[1]*4096.f, v0[2]*4096.f, v0[3]*4096.f,\
                              v1[0]*4096.f, v1[1]*4096.f, v1[2]*4096.f, v1[3]*4096.f};\
                f16x8 a0, a1;                                                   \
                _Pragma("unroll")                                               \
                for (int j = 0; j < 4; ++j) {                                   \
                    h16x2 hp = __builtin_amdgcn_cvt_pkrtz(c[2*j], c[2*j+1]);    \
                    float r0 = c[2*j]   - (float)hp[0];                         \
                    float r1 = c[2*j+1] - (float)hp[1];                         \
                    h16x2 gp = __builtin_amdgcn_cvt_pkrtz(r0, r1);              \
                    a0[2*j] = (f16)hp[0]; a0[2*j+1] = (f16)hp[1];               \
                    a1[2*j] = (f16)gp[0]; a1[2*j+1] = (f16)gp[1];               \
                }                                                               \
                __builtin_amdgcn_s_setprio(1);                                  \
                acc[mt] = __builtin_amdgcn_mfma_f32_32x32x16_f16(a0, W[kk][0], acc[mt], 0, 0, 0); \
                acc[mt] = __builtin_amdgcn_mfma_f32_32x32x16_f16(a1, W[kk][0], acc[mt], 0, 0, 0); \
                acc[mt] = __builtin_amdgcn_mfma_f32_32x32x16_f16(a0, W[kk][1], acc[mt], 0, 0, 0); \
                acc[mt] = __builtin_amdgcn_mfma_f32_32x32x16_f16(a1, W[kk][1], acc[mt], 0, 0, 0); \
                __builtin_amdgcn_s_setprio(0);                                  \
            }                                                                   \
        }                                                                       \
    }

#define BODY(T, WCUR, WNXT)                                                     \
    {                                                                           \
        asm volatile("s_waitcnt vmcnt(1)" ::: "memory");                        \
        __builtin_amdgcn_sched_barrier(0);                                      \
        __builtin_amdgcn_s_barrier();   /* buf[T%3] complete, COMPUTE(T-1) done everywhere */ \
        const int tw = ((T) + 1 < NITER) ? (T) + 1 : 0;                         \
        LOAD_W(tw, WNXT);                                                       \
        const int ts = ((T) + 2 < NITER) ? (T) + 2 : 0;                         \
        __builtin_amdgcn_global_load_lds(                                       \
            (const AS1 void*)(xc + aoff + ts * 128),                            \
            (AS3 void*)(smem + sb + ldsA), 16, 0, 0);                           \
        COMPUTE(cb, WCUR);                                                      \
        cb = (cb == 2 * STG) ? 0 : cb + STG;                                    \
        sb = (sb == 2 * STG) ? 0 : sb + STG;                                    \
    }

    // prologue (issue order defines vmcnt queue): A(0), W(0), A(1)
    __builtin_amdgcn_global_load_lds((const AS1 void*)(xc + aoff),
                                     (AS3 void*)(smem + ldsA), 16, 0, 0);
    LOAD_W(0, wA);
    __builtin_amdgcn_global_load_lds((const AS1 void*)(xc + aoff + 128),
                                     (AS3 void*)(smem + STG + ldsA), 16, 0, 0);

    int cb = 0, sb = 2 * STG;
    for (int tt = 0; tt < NITER; tt += 2) {
        BODY(tt, wA, wB);
        BODY(tt + 1, wB, wA);
    }
#undef BODY
#undef COMPUTE
#undef LOAD_W

    // epilogue: 32x32 C layout: col=l31, row=(r&3)+8*(r>>2)+4*lhi
    float* P = part + (size_t)bz * T_TOKENS * NEXP;
    const int gcol = wcn * 32 + l31;
#pragma unroll
    for (int mt = 0; mt < 2; ++mt)
#pragma unroll
        for (int r = 0; r < 16; ++r) {
            const int row32 = (r & 3) + 8 * (r >> 2) + 4 * lhi;
            const int grow = bm * 64 + mt * 32 + row32;
            P[(size_t)grow * NEXP + gcol] = acc[mt][r];
        }
}

// ---------------- Routing: one wave per token (identical logic since R1) ----------------
__global__ __launch_bounds__(256) void routing_kernel(const float* __restrict__ part,
                                                      const float* __restrict__ bias,
                                                      float* __restrict__ out) {
    const int lane = threadIdx.x & 63;
    const int t = blockIdx.x * 4 + (threadIdx.x >> 6);

    f32x4 z = {0.f, 0.f, 0.f, 0.f};
#pragma unroll
    for (int s = 0; s < NSPLIT; ++s) {
        const f32x4 v = *((const f32x4*)(part + ((size_t)s * T_TOKENS + t) * NEXP) + lane);
        z[0] += v[0]; z[1] += v[1]; z[2] += v[2]; z[3] += v[3];
    }
    const float s0 = 1.0f / (1.0f + expf(-z[0] * UNSCALE));
    const float s1 = 1.0f / (1.0f + expf(-z[1] * UNSCALE));
    const float s2 = 1.0f / (1.0f + expf(-z[2] * UNSCALE));
    const float s3 = 1.0f / (1.0f + expf(-z[3] * UNSCALE));
    const f32x4 bv = *((const f32x4*)bias + lane);
    float sb0 = s0 + bv[0], sb1 = s1 + bv[1], sb2 = s2 + bv[2], sb3 = s3 + bv[3];

    float m1, m2;
    m1 = sb0; m2 = NEG_INF;
    if (sb1 > m1) { m2 = m1; m1 = sb1; } else if (sb1 > m2) m2 = sb1;
    if (sb2 > m1) { m2 = m1; m1 = sb2; } else if (sb2 > m2) m2 = sb2;
    if (sb3 > m1) { m2 = m1; m1 = sb3; } else if (sb3 > m2) m2 = sb3;
#pragma unroll
    for (int off = 1; off < 8; off <<= 1) {
        const float om1 = __shfl_xor(m1, off);
        const float om2 = __shfl_xor(m2, off);
        const float hi = fmaxf(m1, om1);
        const float lo = fminf(m1, om1);
        m2 = fmaxf(lo, fmaxf(m2, om2));
        m1 = hi;
    }
    const float gs = m1 + m2;

    const float g0 = __shfl(gs, 0),  g1 = __shfl(gs, 8),  g2 = __shfl(gs, 16), g3 = __shfl(gs, 24);
    const float g4 = __shfl(gs, 32), g5 = __shfl(gs, 40), g6 = __shfl(gs, 48), g7 = __shfl(gs, 56);

    float t1 = NEG_INF, t2 = NEG_INF, t3 = NEG_INF, t4 = NEG_INF;
    int i1 = 0, i2 = 0, i3 = 0, i4 = 0;
#define INS4(v, gi)                                                         \
    {                                                                       \
        if (v > t1)      { t4=t3;i4=i3; t3=t2;i3=i2; t2=t1;i2=i1; t1=v;i1=gi; } \
        else if (v > t2) { t4=t3;i4=i3; t3=t2;i3=i2; t2=v;i2=gi; }          \
        else if (v > t3) { t4=t3;i4=i3; t3=v;i3=gi; }                       \
        else if (v > t4) { t4=v;i4=gi; }                                    \
    }
    INS4(g0, 0) INS4(g1, 1) INS4(g2, 2) INS4(g3, 3)
    INS4(g4, 4) INS4(g5, 5) INS4(g6, 6) INS4(g7, 7)
#undef INS4
    const int keepmask = (1 << i1) | (1 << i2) | (1 << i3) | (1 << i4);

    const int g = lane >> 3;
    if (!((keepmask >> g) & 1)) { sb0 = NEG_INF; sb1 = NEG_INF; sb2 = NEG_INF; sb3 = NEG_INF; }

    float wval[8];
    int wi[8];
    float wsum = 0.0f;
#pragma unroll
    for (int r = 0; r < 8; r++) {
        float bvv = sb0;
        int bii = (lane << 2);
        if (sb1 > bvv) { bvv = sb1; bii = (lane << 2) | 1; }
        if (sb2 > bvv) { bvv = sb2; bii = (lane << 2) | 2; }
        if (sb3 > bvv) { bvv = sb3; bii = (lane << 2) | 3; }
#pragma unroll
        for (int off = 1; off < 64; off <<= 1) {
            const float ov = __shfl_xor(bvv, off);
            const int oi = __shfl_xor(bii, off);
            if (ov > bvv || (ov == bvv && oi < bii)) { bvv = ov; bii = oi; }
        }
        const int sl = bii & 3;
        const float cand = (sl == 0) ? s0 : (sl == 1) ? s1 : (sl == 2) ? s2 : s3;
        const float ow = __shfl(cand, bii >> 2);
        wval[r] = ow;
        wi[r] = bii;
        wsum += ow;
        if ((bii >> 2) == lane) {
            if (sl == 0) sb0 = NEG_INF;
            else if (sl == 1) sb1 = NEG_INF;
            else if (sl == 2) sb2 = NEG_INF;
            else sb3 = NEG_INF;
        }
    }
    const float scale = 2.5f / wsum;
    if (lane == 0) {
        float* ow8 = out + (size_t)t * 8;
        float* oi8 = out + (size_t)T_TOKENS * 8 + (size_t)t * 8;
#pragma unroll
        for (int r = 0; r < 8; r++) {
            ow8[r] = wval[r] * scale;
            oi8[r] = (float)wi[r];
        }
    }
}

extern "C" void kernel_launch(void* const* d_in, const int* in_sizes, int n_in,
                              void* d_out, int out_size, void* d_ws, size_t ws_size,
                              hipStream_t stream) {
    const float* x = (const float*)d_in[0];
    const float* w = (const float*)d_in[1];
    const float* bias = (const float*)d_in[2];

    char* wt = (char*)d_ws;
    float* part = (float*)((char*)d_ws + PART_OFF);

    wconvert<<<NEXP * DIM / (256 * 8), 256, 0, stream>>>(w, wt);
    gemm_fo<<<512, 512, 0, stream>>>(x, wt, part);
    routing_kernel<<<T_TOKENS / 4, 256, 0, stream>>>(part, bias, (float*)d_out);
}

// Round 13
// 163.106 us; speedup vs baseline: 1.0407x; 1.0407x over previous
//
#include <hip/hip_runtime.h>
#include <math.h>

#define T_TOKENS 8192
#define NEXP 256
#define DIM 7168
#define NSPLIT 4
#define KSPL (DIM / NSPLIT)      // 1792
#define NITER (KSPL / 32)        // 56 K-steps per bz
#define NEG_INF (-3.0e38f)

typedef _Float16 f16;
typedef _Float16 f16x8 __attribute__((ext_vector_type(8)));
typedef __fp16 h16x2 __attribute__((ext_vector_type(2)));
typedef float f32x4 __attribute__((ext_vector_type(4)));
typedef float f32x16 __attribute__((ext_vector_type(16)));

#define AS1 __attribute__((address_space(1)))
#define AS3 __attribute__((address_space(3)))

// ws: [W' frag-tiled f16 7.34MB][part f32 (NSPLIT x T x E) 33.5MB]
// W' 32KB chunk per K-step T; unit (kk*2+p)*8 + ntg (1KB, lane-contiguous:
// lane l of unit holds w[e = ntg*32 + (l&31)][32T + kk*16 + (l>>5)*8 .. +7], plane p)
#define WTILED_BYTES (2 * NEXP * DIM * 2)   // 7,340,032
#define PART_OFF WTILED_BYTES
#define UNSCALE 5.9604644775390625e-8f      // 2^-24 exact
#define STG 40960                            // stage: A 8KB (frag order) + W' chunk 32KB

// ---------------- prologue: w (f32) -> 32x32-frag-tiled 2-plane f16 image ----------------
__global__ __launch_bounds__(256) void wconvert(const float* __restrict__ w,
                                                char* __restrict__ wt) {
    const int n = blockIdx.x * 256 + threadIdx.x;   // 0 .. 229375
    const int K8 = n % 896;                         // k-octet
    const int e = n / 896;                          // expert 0..255
    const f32x4 u0 = *(const f32x4*)(w + (size_t)e * DIM + K8 * 8);
    const f32x4 u1 = *(const f32x4*)(w + (size_t)e * DIM + K8 * 8 + 4);
    float c[8] = {u0[0]*4096.f, u0[1]*4096.f, u0[2]*4096.f, u0[3]*4096.f,
                  u1[0]*4096.f, u1[1]*4096.f, u1[2]*4096.f, u1[3]*4096.f};
    f16x8 h, g;
#pragma unroll
    for (int j = 0; j < 4; ++j) {
        h16x2 hp = __builtin_amdgcn_cvt_pkrtz(c[2*j], c[2*j+1]);
        float r0 = c[2*j]   - (float)hp[0];
        float r1 = c[2*j+1] - (float)hp[1];
        h16x2 gp = __builtin_amdgcn_cvt_pkrtz(r0, r1);
        h[2*j] = (f16)hp[0]; h[2*j+1] = (f16)hp[1];
        g[2*j] = (f16)gp[0]; g[2*j+1] = (f16)gp[1];
    }
    const int T = K8 >> 2;                  // K-step
    const int kk = (K8 >> 1) & 1;
    const int lhi = K8 & 1;
    const int ntg = e >> 5, l31 = e & 31;
    char* base = wt + (size_t)T * 32768 + ntg * 1024 + lhi * 512 + l31 * 16;
    *(f16x8*)(base + (kk * 2 + 0) * 8192) = h;
    *(f16x8*)(base + (kk * 2 + 1) * 8192) = g;
}

// ---------------- GEMM: BN=256, wave tile 32x64, ring-2 LDS, 1 barrier/K-step ----------------
// grid 512 (2/CU); 512 threads = 8 waves (2 wm x 4 wn); block tile 64x256.
// Stage (40KB): [A frag-order 8KB: unit(mt,kk,j)=mt*4+kk*2+j][W' chunk 32KB].
// Sync: BODY(T): vmcnt(0) (only S(T) outstanding; issued one full compute phase
// ago) -> s_barrier (S(T) landed everywhere; COMPUTE(T-1) done everywhere) ->
// issue S(T+1) into buf^1 (the buffer COMPUTE(T-1) just finished) -> COMPUTE(T).
__global__ __launch_bounds__(512, 4) void gemm_bn(
    const float* __restrict__ x, const char* __restrict__ wt,
    float* __restrict__ part) {
    extern __shared__ __align__(16) char smem[];
    const int tid = threadIdx.x;
    const int lane = tid & 63;
    const int wcn = tid >> 6;                // wave 0..7
    const int wm = wcn >> 2, wn = wcn & 3;   // 2 x 4 wave grid
    // XCD-pin: xcd -> (bz, bm-half); W' slice (1.83MB) stays in that XCD's L2
    const int b = blockIdx.x;
    const int xcd = b & 7;
    const int bz = xcd >> 1;
    const int bm = (xcd & 1) * 64 + (b >> 3);   // 0..127 (BM=64 rows)
    const int l31 = lane & 31, lhi = lane >> 5;

    const char* xc = (const char*)x;

    // A staging: wave wcn stages unit u=wcn (mt_s,kk_s,j_s), per-lane frag-order source
    const int mt_s = wcn >> 2, kk_s = (wcn >> 1) & 1, j_s = wcn & 1;
    const int aoff = ((bm * 64 + mt_s * 32 + l31) * DIM + bz * KSPL
                      + kk_s * 16 + lhi * 8 + j_s * 4) * 4;
    const int ldsA = wcn * 1024;
    // W staging: wave wcn stages units wcn*4..wcn*4+3 (linear 1KB each)
    const char* wsrc = wt + (size_t)bz * NITER * 32768;
    const int woffb = wcn * 4096 + lane * 16;
    const int ldsW = 8192 + wcn * 4096;

    // A fragment reads: this wave's M-tile wm; units wm*4 + kk*2 + j
    // W fragment reads: units (kk*2+p)*8 + wn*2 + ntl
    f32x16 acc[2];
#pragma unroll
    for (int ntl = 0; ntl < 2; ++ntl)
#pragma unroll
        for (int r = 0; r < 16; ++r) acc[ntl][r] = 0.0f;

#define STAGE(T, SB)                                                            \
    {                                                                           \
        __builtin_amdgcn_global_load_lds(                                       \
            (const AS1 void*)(xc + aoff + (T) * 128),                           \
            (AS3 void*)(smem + (SB) + ldsA), 16, 0, 0);                         \
        _Pragma("unroll")                                                       \
        for (int i = 0; i < 4; ++i)                                             \
            __builtin_amdgcn_global_load_lds(                                   \
                (const AS1 void*)(wsrc + (size_t)(T) * 32768 + woffb + i * 1024),\
                (AS3 void*)(smem + (SB) + ldsW + i * 1024), 16, 0, 0);          \
    }

#define COMPUTE(CB)                                                             \
    {                                                                           \
        _Pragma("unroll")                                                       \
        for (int kk = 0; kk < 2; ++kk) {                                        \
            const f32x4 v0 = *(const f32x4*)(smem + (CB) + (wm * 4 + kk * 2 + 0) * 1024 + lane * 16); \
            const f32x4 v1 = *(const f32x4*)(smem + (CB) + (wm * 4 + kk * 2 + 1) * 1024 + lane * 16); \
            float c[8] = {v0[0]*4096.f, v0[1]*4096.f, v0[2]*4096.f, v0[3]*4096.f,\
                          v1[0]*4096.f, v1[1]*4096.f, v1[2]*4096.f, v1[3]*4096.f};\
            f16x8 a0, a1;                                                       \
            _Pragma("unroll")                                                   \
            for (int j = 0; j < 4; ++j) {                                       \
                h16x2 hp = __builtin_amdgcn_cvt_pkrtz(c[2*j], c[2*j+1]);        \
                float r0 = c[2*j]   - (float)hp[0];                             \
                float r1 = c[2*j+1] - (float)hp[1];                             \
                h16x2 gp = __builtin_amdgcn_cvt_pkrtz(r0, r1);                  \
                a0[2*j] = (f16)hp[0]; a0[2*j+1] = (f16)hp[1];                   \
                a1[2*j] = (f16)gp[0]; a1[2*j+1] = (f16)gp[1];                   \
            }                                                                   \
            f16x8 wb[2][2];                                                     \
            _Pragma("unroll")                                                   \
            for (int p = 0; p < 2; ++p)                                         \
                _Pragma("unroll")                                               \
                for (int ntl = 0; ntl < 2; ++ntl)                               \
                    wb[p][ntl] = *(const f16x8*)(smem + (CB) + 8192             \
                        + ((kk * 2 + p) * 8 + wn * 2 + ntl) * 1024 + lane * 16);\
            __builtin_amdgcn_s_setprio(1);                                      \
            _Pragma("unroll")                                                   \
            for (int ntl = 0; ntl < 2; ++ntl) {                                 \
                acc[ntl] = __builtin_amdgcn_mfma_f32_32x32x16_f16(a0, wb[0][ntl], acc[ntl], 0, 0, 0); \
                acc[ntl] = __builtin_amdgcn_mfma_f32_32x32x16_f16(a1, wb[0][ntl], acc[ntl], 0, 0, 0); \
                acc[ntl] = __builtin_amdgcn_mfma_f32_32x32x16_f16(a0, wb[1][ntl], acc[ntl], 0, 0, 0); \
                acc[ntl] = __builtin_amdgcn_mfma_f32_32x32x16_f16(a1, wb[1][ntl], acc[ntl], 0, 0, 0); \
            }                                                                   \
            __builtin_amdgcn_s_setprio(0);                                      \
        }                                                                       \
    }

    // prologue: S(0) -> buf0
    STAGE(0, 0);
    for (int t = 0; t < NITER; ++t) {
        asm volatile("s_waitcnt vmcnt(0)" ::: "memory");
        __builtin_amdgcn_sched_barrier(0);
        __builtin_amdgcn_s_barrier();
        const int tn = (t + 1 < NITER) ? t + 1 : 0;
        STAGE(tn, ((t + 1) & 1) * STG);
        COMPUTE((t & 1) * STG);
    }
#undef STAGE
#undef COMPUTE

    // epilogue: 32x32 C layout: col=l31, row=(r&3)+8*(r>>2)+4*lhi
    float* P = part + (size_t)bz * T_TOKENS * NEXP;
#pragma unroll
    for (int ntl = 0; ntl < 2; ++ntl) {
        const int gcol = wn * 64 + ntl * 32 + l31;
#pragma unroll
        for (int r = 0; r < 16; ++r) {
            const int row32 = (r & 3) + 8 * (r >> 2) + 4 * lhi;
            const int grow = bm * 64 + wm * 32 + row32;
            P[(size_t)grow * NEXP + gcol] = acc[ntl][r];
        }
    }
}

// ---------------- Routing: one wave per token (identical logic since R1) ----------------
__global__ __launch_bounds__(256) void routing_kernel(const float* __restrict__ part,
                                                      const float* __restrict__ bias,
                                                      float* __restrict__ out) {
    const int lane = threadIdx.x & 63;
    const int t = blockIdx.x * 4 + (threadIdx.x >> 6);

    f32x4 z = {0.f, 0.f, 0.f, 0.f};
#pragma unroll
    for (int s = 0; s < NSPLIT; ++s) {
        const f32x4 v = *((const f32x4*)(part + ((size_t)s * T_TOKENS + t) * NEXP) + lane);
        z[0] += v[0]; z[1] += v[1]; z[2] += v[2]; z[3] += v[3];
    }
    const float s0 = 1.0f / (1.0f + expf(-z[0] * UNSCALE));
    const float s1 = 1.0f / (1.0f + expf(-z[1] * UNSCALE));
    const float s2 = 1.0f / (1.0f + expf(-z[2] * UNSCALE));
    const float s3 = 1.0f / (1.0f + expf(-z[3] * UNSCALE));
    const f32x4 bv = *((const f32x4*)bias + lane);
    float sb0 = s0 + bv[0], sb1 = s1 + bv[1], sb2 = s2 + bv[2], sb3 = s3 + bv[3];

    float m1, m2;
    m1 = sb0; m2 = NEG_INF;
    if (sb1 > m1) { m2 = m1; m1 = sb1; } else if (sb1 > m2) m2 = sb1;
    if (sb2 > m1) { m2 = m1; m1 = sb2; } else if (sb2 > m2) m2 = sb2;
    if (sb3 > m1) { m2 = m1; m1 = sb3; } else if (sb3 > m2) m2 = sb3;
#pragma unroll
    for (int off = 1; off < 8; off <<= 1) {
        const float om1 = __shfl_xor(m1, off);
        const float om2 = __shfl_xor(m2, off);
        const float hi = fmaxf(m1, om1);
        const float lo = fminf(m1, om1);
        m2 = fmaxf(lo, fmaxf(m2, om2));
        m1 = hi;
    }
    const float gs = m1 + m2;

    const float g0 = __shfl(gs, 0),  g1 = __shfl(gs, 8),  g2 = __shfl(gs, 16), g3 = __shfl(gs, 24);
    const float g4 = __shfl(gs, 32), g5 = __shfl(gs, 40), g6 = __shfl(gs, 48), g7 = __shfl(gs, 56);

    float t1 = NEG_INF, t2 = NEG_INF, t3 = NEG_INF, t4 = NEG_INF;
    int i1 = 0, i2 = 0, i3 = 0, i4 = 0;
#define INS4(v, gi)                                                         \
    {                                                                       \
        if (v > t1)      { t4=t3;i4=i3; t3=t2;i3=i2; t2=t1;i2=i1; t1=v;i1=gi; } \
        else if (v > t2) { t4=t3;i4=i3; t3=t2;i3=i2; t2=v;i2=gi; }          \
        else if (v > t3) { t4=t3;i4=i3; t3=v;i3=gi; }                       \
        else if (v > t4) { t4=v;i4=gi; }                                    \
    }
    INS4(g0, 0) INS4(g1, 1) INS4(g2, 2) INS4(g3, 3)
    INS4(g4, 4) INS4(g5, 5) INS4(g6, 6) INS4(g7, 7)
#undef INS4
    const int keepmask = (1 << i1) | (1 << i2) | (1 << i3) | (1 << i4);

    const int g = lane >> 3;
    if (!((keepmask >> g) & 1)) { sb0 = NEG_INF; sb1 = NEG_INF; sb2 = NEG_INF; sb3 = NEG_INF; }

    float wval[8];
    int wi[8];
    float wsum = 0.0f;
#pragma unroll
    for (int r = 0; r < 8; r++) {
        float bvv = sb0;
        int bii = (lane << 2);
        if (sb1 > bvv) { bvv = sb1; bii = (lane << 2) | 1; }
        if (sb2 > bvv) { bvv = sb2; bii = (lane << 2) | 2; }
        if (sb3 > bvv) { bvv = sb3; bii = (lane << 2) | 3; }
#pragma unroll
        for (int off = 1; off < 64; off <<= 1) {
            const float ov = __shfl_xor(bvv, off);
            const int oi = __shfl_xor(bii, off);
            if (ov > bvv || (ov == bvv && oi < bii)) { bvv = ov; bii = oi; }
        }
        const int sl = bii & 3;
        const float cand = (sl == 0) ? s0 : (sl == 1) ? s1 : (sl == 2) ? s2 : s3;
        const float ow = __shfl(cand, bii >> 2);
        wval[r] = ow;
        wi[r] = bii;
        wsum += ow;
        if ((bii >> 2) == lane) {
            if (sl == 0) sb0 = NEG_INF;
            else if (sl == 1) sb1 = NEG_INF;
            else if (sl == 2) sb2 = NEG_INF;
            else sb3 = NEG_INF;
        }
    }
    const float scale = 2.5f / wsum;
    if (lane == 0) {
        float* ow8 = out + (size_t)t * 8;
        float* oi8 = out + (size_t)T_TOKENS * 8 + (size_t)t * 8;
#pragma unroll
        for (int r = 0; r < 8; r++) {
            ow8[r] = wval[r] * scale;
            oi8[r] = (float)wi[r];
        }
    }
}

extern "C" void kernel_launch(void* const* d_in, const int* in_sizes, int n_in,
                              void* d_out, int out_size, void* d_ws, size_t ws_size,
                              hipStream_t stream) {
    const float* x = (const float*)d_in[0];
    const float* w = (const float*)d_in[1];
    const float* bias = (const float*)d_in[2];

    char* wt = (char*)d_ws;
    float* part = (float*)((char*)d_ws + PART_OFF);

    // 80KB dynamic LDS opt-in (2 blocks/CU at 160KB/CU). Deterministic, capture-safe.
    (void)hipFuncSetAttribute((const void*)gemm_bn,
                              hipFuncAttributeMaxDynamicSharedMemorySize, 2 * STG);

    wconvert<<<NEXP * DIM / (256 * 8), 256, 0, stream>>>(w, wt);
    gemm_bn<<<512, 512, 2 * STG, stream>>>(x, wt, part);
    routing_kernel<<<T_TOKENS / 4, 256, 0, stream>>>(part, bias, (float*)d_out);
}